// Round 2
// baseline (632.388 us; speedup 1.0000x reference)
//
#include <hip/hip_runtime.h>
#include <cstdint>
#include <cstddef>

typedef unsigned short u16;
typedef __attribute__((ext_vector_type(8))) short bf16x8;
typedef __attribute__((ext_vector_type(4))) float f32x4;
typedef __attribute__((address_space(1))) const unsigned int gu32;
typedef __attribute__((address_space(3))) unsigned int lu32;

#define LOG2E 1.44269504088896340736f

__device__ __forceinline__ u16 f2bf(float f) {
  uint32_t u = __float_as_uint(f);
  u += 0x7fffu + ((u >> 16) & 1u);
  return (u16)(u >> 16);
}

// ---------------- transpose fp32 (K,N) -> bf16 (N,K) ----------------
__global__ __launch_bounds__(256) void transpose_w(const float* __restrict__ W,
                                                   u16* __restrict__ WT,
                                                   int K, int N) {
  __shared__ float t[32][33];
  int n0 = blockIdx.x * 32, k0 = blockIdx.y * 32;
  for (int i = threadIdx.y; i < 32; i += 8)
    t[i][threadIdx.x] = W[(size_t)(k0 + i) * N + n0 + threadIdx.x];
  __syncthreads();
  for (int i = threadIdx.y; i < 32; i += 8)
    WT[(size_t)(n0 + i) * K + k0 + threadIdx.x] = f2bf(t[threadIdx.x][i]);
}

// ---------------- layernorm fp32 row(1024) -> bf16 ----------------
__global__ __launch_bounds__(256) void ln_kernel(const float* __restrict__ x,
                                                 const float* __restrict__ g,
                                                 const float* __restrict__ b,
                                                 u16* __restrict__ out) {
  int row = blockIdx.x;
  const float4 v = *(const float4*)(x + (size_t)row * 1024 + threadIdx.x * 4);
  float s = v.x + v.y + v.z + v.w;
  float ss = v.x * v.x + v.y * v.y + v.z * v.z + v.w * v.w;
#pragma unroll
  for (int d = 1; d < 64; d <<= 1) { s += __shfl_xor(s, d); ss += __shfl_xor(ss, d); }
  __shared__ float rs_[4], rss_[4];
  int wv = threadIdx.x >> 6;
  if ((threadIdx.x & 63) == 0) { rs_[wv] = s; rss_[wv] = ss; }
  __syncthreads();
  s = rs_[0] + rs_[1] + rs_[2] + rs_[3];
  ss = rss_[0] + rss_[1] + rss_[2] + rss_[3];
  float mu = s * (1.f / 1024.f);
  float var = ss * (1.f / 1024.f) - mu * mu;
  float rstd = rsqrtf(var + 1e-5f);
  float4 gv = *(const float4*)(g + threadIdx.x * 4);
  float4 bv = *(const float4*)(b + threadIdx.x * 4);
  uint32_t lo = (uint32_t)f2bf((v.x - mu) * rstd * gv.x + bv.x) |
                ((uint32_t)f2bf((v.y - mu) * rstd * gv.y + bv.y) << 16);
  uint32_t hi = (uint32_t)f2bf((v.z - mu) * rstd * gv.z + bv.z) |
                ((uint32_t)f2bf((v.w - mu) * rstd * gv.w + bv.w) << 16);
  uint2 o; o.x = lo; o.y = hi;
  *(uint2*)(out + (size_t)row * 1024 + threadIdx.x * 4) = o;
}

// ---------------- GEMM (m97 structure): C = A(bf16 MxK) * BT(bf16 NxK) ----------------
// global_load_lds width-16 staging, linear LDS stride BK.
// MODE 0: QKV  (N=3072) -> Q[B,H,T,HD]*0.125 / K[B,H,T,HD] / VT[B,H,HD,T]
// MODE 1: PROJ -> outf = acc + bias + resid      (fp32)
// MODE 2: FF1  -> ob0  = bf16(relu(acc + bias))
// MODE 3: FF2  -> outf = relu(acc + bias) + resid (fp32)
#define BM 128
#define BN 128
#define BK 64

template <int MODE>
__global__ __launch_bounds__(256) void gemm_bt(
    const u16* __restrict__ A, const u16* __restrict__ BT,
    int M, int N, int K,
    const float* __restrict__ bias, const float* __restrict__ resid,
    float* __restrict__ outf,
    u16* __restrict__ ob0, u16* __restrict__ ob1, u16* __restrict__ ob2) {
  __shared__ u16 As[BM * BK];
  __shared__ u16 Bs[BN * BK];
  const int tid = threadIdx.x, lane = tid & 63;
  const int wr = (tid >> 6) >> 1, wc = (tid >> 6) & 1;
  const int bm = blockIdx.y, bn = blockIdx.x;
  const int l15 = lane & 15, lhi = lane >> 4;
  const int srow = tid >> 3, scol = (tid & 7) * 8;  // 8 elems (16B) per thread per issue
  const int wv512 = (tid >> 6) * 512;               // wave-uniform LDS base (elems)

  f32x4 acc[4][4];
#pragma unroll
  for (int i = 0; i < 4; ++i)
#pragma unroll
    for (int j = 0; j < 4; ++j) acc[i][j] = (f32x4){0.f, 0.f, 0.f, 0.f};

  for (int kt = 0; kt < K; kt += BK) {
    __syncthreads();
#pragma unroll
    for (int c = 0; c < 4; ++c) {
      int row = c * 32 + srow;
      __builtin_amdgcn_global_load_lds(
          (gu32*)(A + (size_t)(bm * BM + row) * K + kt + scol),
          (lu32*)&As[c * 2048 + wv512], 16, 0, 0);
      __builtin_amdgcn_global_load_lds(
          (gu32*)(BT + (size_t)(bn * BN + row) * K + kt + scol),
          (lu32*)&Bs[c * 2048 + wv512], 16, 0, 0);
    }
    __syncthreads();
#pragma unroll
    for (int ks = 0; ks < 2; ++ks) {
      bf16x8 af[4], bf[4];
#pragma unroll
      for (int i = 0; i < 4; ++i)
        af[i] = *(const bf16x8*)&As[(wr * 64 + i * 16 + l15) * BK + ks * 32 + lhi * 8];
#pragma unroll
      for (int j = 0; j < 4; ++j)
        bf[j] = *(const bf16x8*)&Bs[(wc * 64 + j * 16 + l15) * BK + ks * 32 + lhi * 8];
#pragma unroll
      for (int i = 0; i < 4; ++i)
#pragma unroll
        for (int j = 0; j < 4; ++j)
          acc[i][j] = __builtin_amdgcn_mfma_f32_16x16x32_bf16(af[i], bf[j], acc[i][j], 0, 0, 0);
    }
  }

#pragma unroll
  for (int i = 0; i < 4; ++i) {
#pragma unroll
    for (int j = 0; j < 4; ++j) {
      int col = bn * BN + wc * 64 + j * 16 + l15;
      int rbase = bm * BM + wr * 64 + i * 16 + lhi * 4;
#pragma unroll
      for (int r = 0; r < 4; ++r) {
        float v = acc[i][j][r];
        int rg = rbase + r;
        if (MODE == 0) {
          int b = rg >> 11, t = rg & 2047;
          int cm = col & 1023, h = cm >> 6, d = cm & 63;
          size_t bh = (size_t)(b * 16 + h);
          if (col < 1024)
            ob0[(bh * 2048 + t) * 64 + d] = f2bf(v * 0.125f);
          else if (col < 2048)
            ob1[(bh * 2048 + t) * 64 + d] = f2bf(v);
          else
            ob2[(bh * 64 + d) * 2048 + t] = f2bf(v);
        } else if (MODE == 1) {
          outf[(size_t)rg * N + col] = v + bias[col] + resid[(size_t)rg * N + col];
        } else if (MODE == 2) {
          ob0[(size_t)rg * N + col] = f2bf(fmaxf(v + bias[col], 0.f));
        } else {
          outf[(size_t)rg * N + col] = fmaxf(v + bias[col], 0.f) + resid[(size_t)rg * N + col];
        }
      }
    }
  }
}

// ---------------- causal flash attention ----------------
// 8 waves x 32 q-rows = QBLK 256 per block; KVBLK=64.
// Q,K: [B*H, T, 64] bf16 (Q pre-scaled by 1/8); VT: [B*H, 64, T] bf16
// O: [B*T, 1024] bf16
__global__ __launch_bounds__(512) void attn_kernel(
    const u16* __restrict__ Qb, const u16* __restrict__ Kb,
    const u16* __restrict__ VTb, u16* __restrict__ O) {
  const int qt = (int)gridDim.x - 1 - (int)blockIdx.x;  // long blocks first
  const int bh = blockIdx.y;
  const u16* Q = Qb + (size_t)bh * 2048 * 64;
  const u16* Kp = Kb + (size_t)bh * 2048 * 64;
  const u16* VT = VTb + (size_t)bh * 64 * 2048;
  const int tid = threadIdx.x, lane = tid & 63, wv = tid >> 6;
  const int l15 = lane & 15, lhi = lane >> 4;

  __shared__ u16 Ks[64 * 72];
  __shared__ u16 Vs[64 * 72];
  __shared__ u16 Ps[8][32 * 72];

  const int qbase = qt * 256 + wv * 32;

  bf16x8 qf[2][2];
#pragma unroll
  for (int rf = 0; rf < 2; ++rf)
#pragma unroll
    for (int ks = 0; ks < 2; ++ks)
      qf[rf][ks] = *(const bf16x8*)&Q[(size_t)(qbase + rf * 16 + l15) * 64 + ks * 32 + lhi * 8];

  f32x4 o[2][4];
  float m[2][4], l[2][4];
#pragma unroll
  for (int rf = 0; rf < 2; ++rf)
#pragma unroll
    for (int f = 0; f < 4; ++f) o[rf][f] = (f32x4){0.f, 0.f, 0.f, 0.f};
#pragma unroll
  for (int rf = 0; rf < 2; ++rf)
#pragma unroll
    for (int r = 0; r < 4; ++r) { m[rf][r] = -1e30f; l[rf][r] = 0.f; }

  const int srow = tid >> 3, scol = (tid & 7) * 8;  // 512 thr x 8 elems = 64x64 tile
  const int ktmax = qt * 4 + 3;

  for (int kt = 0; kt <= ktmax; ++kt) {
    __syncthreads();
    *(bf16x8*)&Ks[srow * 72 + scol] =
        *(const bf16x8*)&Kp[((size_t)kt * 64 + srow) * 64 + scol];
    *(bf16x8*)&Vs[srow * 72 + scol] =
        *(const bf16x8*)&VT[(size_t)srow * 2048 + kt * 64 + scol];
    __syncthreads();

    if (kt * 64 > qbase + 31) continue;  // tile fully masked for this wave

    f32x4 s[2][4];
#pragma unroll
    for (int rf = 0; rf < 2; ++rf)
#pragma unroll
      for (int j = 0; j < 4; ++j) s[rf][j] = (f32x4){0.f, 0.f, 0.f, 0.f};
#pragma unroll
    for (int ks = 0; ks < 2; ++ks)
#pragma unroll
      for (int j = 0; j < 4; ++j) {
        bf16x8 kf = *(const bf16x8*)&Ks[(j * 16 + l15) * 72 + ks * 32 + lhi * 8];
        s[0][j] = __builtin_amdgcn_mfma_f32_16x16x32_bf16(qf[0][ks], kf, s[0][j], 0, 0, 0);
        s[1][j] = __builtin_amdgcn_mfma_f32_16x16x32_bf16(qf[1][ks], kf, s[1][j], 0, 0, 0);
      }

    if (kt * 64 + 63 > qbase) {  // diagonal-crossing: apply causal mask
#pragma unroll
      for (int rf = 0; rf < 2; ++rf)
#pragma unroll
        for (int j = 0; j < 4; ++j)
#pragma unroll
          for (int r = 0; r < 4; ++r) {
            int qg = qbase + rf * 16 + lhi * 4 + r;
            int kg = kt * 64 + j * 16 + l15;
            if (kg > qg) s[rf][j][r] = -1e30f;
          }
    }

#pragma unroll
    for (int rf = 0; rf < 2; ++rf)
#pragma unroll
      for (int r = 0; r < 4; ++r) {
        float pm = fmaxf(fmaxf(s[rf][0][r], s[rf][1][r]), fmaxf(s[rf][2][r], s[rf][3][r]));
#pragma unroll
        for (int d = 1; d < 16; d <<= 1) pm = fmaxf(pm, __shfl_xor(pm, d));
        float mn = fmaxf(m[rf][r], pm);
        float sc = exp2f((m[rf][r] - mn) * LOG2E);
        float rowsum = 0.f;
#pragma unroll
        for (int j = 0; j < 4; ++j) {
          float pv = exp2f((s[rf][j][r] - mn) * LOG2E);
          s[rf][j][r] = pv;
          rowsum += pv;
        }
#pragma unroll
        for (int d = 1; d < 16; d <<= 1) rowsum += __shfl_xor(rowsum, d);
        l[rf][r] = l[rf][r] * sc + rowsum;
        m[rf][r] = mn;
#pragma unroll
        for (int f = 0; f < 4; ++f) o[rf][f][r] *= sc;
      }

#pragma unroll
    for (int rf = 0; rf < 2; ++rf)
#pragma unroll
      for (int j = 0; j < 4; ++j)
#pragma unroll
        for (int r = 0; r < 4; ++r)
          Ps[wv][(rf * 16 + lhi * 4 + r) * 72 + j * 16 + l15] = f2bf(s[rf][j][r]);
    // Ps is wave-private: no barrier needed (lgkmcnt dependence handled by compiler)
#pragma unroll
    for (int ks = 0; ks < 2; ++ks) {
      bf16x8 pf0 = *(const bf16x8*)&Ps[wv][(l15) * 72 + ks * 32 + lhi * 8];
      bf16x8 pf1 = *(const bf16x8*)&Ps[wv][(16 + l15) * 72 + ks * 32 + lhi * 8];
#pragma unroll
      for (int f = 0; f < 4; ++f) {
        bf16x8 vfr = *(const bf16x8*)&Vs[(f * 16 + l15) * 72 + ks * 32 + lhi * 8];
        o[0][f] = __builtin_amdgcn_mfma_f32_16x16x32_bf16(pf0, vfr, o[0][f], 0, 0, 0);
        o[1][f] = __builtin_amdgcn_mfma_f32_16x16x32_bf16(pf1, vfr, o[1][f], 0, 0, 0);
      }
    }
  }

  const int b = bh >> 4, h = bh & 15;
#pragma unroll
  for (int rf = 0; rf < 2; ++rf)
#pragma unroll
    for (int r = 0; r < 4; ++r) {
      float inv = 1.f / l[rf][r];
      int t = qbase + rf * 16 + lhi * 4 + r;
#pragma unroll
      for (int f = 0; f < 4; ++f)
        O[((size_t)(b * 2048 + t)) * 1024 + h * 64 + f * 16 + l15] = f2bf(o[rf][f][r] * inv);
    }
}

extern "C" void kernel_launch(void* const* d_in, const int* in_sizes, int n_in,
                              void* d_out, int out_size, void* d_ws, size_t ws_size,
                              hipStream_t stream) {
  const float* x   = (const float*)d_in[0];
  const float* Wq  = (const float*)d_in[1];
  const float* Wk  = (const float*)d_in[2];
  const float* Wv  = (const float*)d_in[3];
  const float* Wo  = (const float*)d_in[4];
  const float* bo  = (const float*)d_in[5];
  const float* W1  = (const float*)d_in[6];
  const float* b1  = (const float*)d_in[7];
  const float* W2  = (const float*)d_in[8];
  const float* b2  = (const float*)d_in[9];
  const float* g1  = (const float*)d_in[10];
  const float* be1 = (const float*)d_in[11];
  const float* g2  = (const float*)d_in[12];
  const float* be2 = (const float*)d_in[13];

  char* p = (char*)d_ws;
  auto alloc = [&](size_t bytes) {
    char* r = p;
    p += (bytes + 255) & ~(size_t)255;
    return r;
  };
  u16* WqkvT = (u16*)alloc(3072ull * 1024 * 2);
  u16* WoT   = (u16*)alloc(1024ull * 1024 * 2);
  u16* W1T   = (u16*)alloc(4096ull * 1024 * 2);
  u16* W2T   = (u16*)alloc(1024ull * 4096 * 2);
  u16* hln   = (u16*)alloc(8192ull * 1024 * 2);
  u16* Qbuf  = (u16*)alloc(8192ull * 1024 * 2);
  u16* Kbuf  = (u16*)alloc(8192ull * 1024 * 2);
  u16* VTbuf = (u16*)alloc(8192ull * 1024 * 2);
  float* x2  = (float*)alloc(8192ull * 1024 * 4);
  u16* ff1   = (u16*)alloc(8192ull * 4096 * 2);
  u16* Oattn = hln;   // hln dead after QKV GEMM
  u16* h2    = Qbuf;  // Qbuf dead after attention
  if ((size_t)(p - (char*)d_ws) > ws_size) return;  // ws too small: bail

  dim3 tb(32, 8);
  transpose_w<<<dim3(32, 32), tb, 0, stream>>>(Wq, WqkvT, 1024, 1024);
  transpose_w<<<dim3(32, 32), tb, 0, stream>>>(Wk, WqkvT + 1024 * 1024, 1024, 1024);
  transpose_w<<<dim3(32, 32), tb, 0, stream>>>(Wv, WqkvT + 2048 * 1024, 1024, 1024);
  transpose_w<<<dim3(32, 32), tb, 0, stream>>>(Wo, WoT, 1024, 1024);
  transpose_w<<<dim3(128, 32), tb, 0, stream>>>(W1, W1T, 1024, 4096);
  transpose_w<<<dim3(32, 128), tb, 0, stream>>>(W2, W2T, 4096, 1024);

  ln_kernel<<<8192, 256, 0, stream>>>(x, g1, be1, hln);

  gemm_bt<0><<<dim3(24, 64), 256, 0, stream>>>(hln, WqkvT, 8192, 3072, 1024,
                                               nullptr, nullptr, nullptr,
                                               Qbuf, Kbuf, VTbuf);

  attn_kernel<<<dim3(8, 64), 512, 0, stream>>>(Qbuf, Kbuf, VTbuf, Oattn);

  gemm_bt<1><<<dim3(8, 64), 256, 0, stream>>>(Oattn, WoT, 8192, 1024, 1024,
                                              bo, x, x2, nullptr, nullptr, nullptr);

  ln_kernel<<<8192, 256, 0, stream>>>(x2, g2, be2, h2);

  gemm_bt<2><<<dim3(32, 64), 256, 0, stream>>>(h2, W1T, 8192, 4096, 1024,
                                               b1, nullptr, nullptr, ff1, nullptr, nullptr);

  gemm_bt<3><<<dim3(8, 64), 256, 0, stream>>>(ff1, W2T, 8192, 1024, 4096,
                                              b2, x2, (float*)d_out, nullptr, nullptr, nullptr);
}

// Round 3
// 491.873 us; speedup vs baseline: 1.2857x; 1.2857x over previous
//
#include <hip/hip_runtime.h>
#include <cstdint>
#include <cstddef>

typedef unsigned short u16;
typedef __attribute__((ext_vector_type(8))) short bf16x8;
typedef __attribute__((ext_vector_type(4))) float f32x4;
typedef __attribute__((ext_vector_type(4))) u16 u16x4;
typedef __attribute__((address_space(1))) const unsigned int gu32;
typedef __attribute__((address_space(3))) unsigned int lu32;

#define LOG2E 1.44269504088896340736f

__device__ __forceinline__ u16 f2bf(float f) {
  uint32_t u = __float_as_uint(f);
  u += 0x7fffu + ((u >> 16) & 1u);
  return (u16)(u >> 16);
}

// ---------------- transpose fp32 (K,N) -> bf16 (N,K) ----------------
__global__ __launch_bounds__(256) void transpose_w(const float* __restrict__ W,
                                                   u16* __restrict__ WT,
                                                   int K, int N) {
  __shared__ float t[32][33];
  int n0 = blockIdx.x * 32, k0 = blockIdx.y * 32;
  for (int i = threadIdx.y; i < 32; i += 8)
    t[i][threadIdx.x] = W[(size_t)(k0 + i) * N + n0 + threadIdx.x];
  __syncthreads();
  for (int i = threadIdx.y; i < 32; i += 8)
    WT[(size_t)(n0 + i) * K + k0 + threadIdx.x] = f2bf(t[threadIdx.x][i]);
}

// ---------------- layernorm fp32 row(1024) -> bf16 ----------------
__global__ __launch_bounds__(256) void ln_kernel(const float* __restrict__ x,
                                                 const float* __restrict__ g,
                                                 const float* __restrict__ b,
                                                 u16* __restrict__ out) {
  int row = blockIdx.x;
  const float4 v = *(const float4*)(x + (size_t)row * 1024 + threadIdx.x * 4);
  float s = v.x + v.y + v.z + v.w;
  float ss = v.x * v.x + v.y * v.y + v.z * v.z + v.w * v.w;
#pragma unroll
  for (int d = 1; d < 64; d <<= 1) { s += __shfl_xor(s, d); ss += __shfl_xor(ss, d); }
  __shared__ float rs_[4], rss_[4];
  int wv = threadIdx.x >> 6;
  if ((threadIdx.x & 63) == 0) { rs_[wv] = s; rss_[wv] = ss; }
  __syncthreads();
  s = rs_[0] + rs_[1] + rs_[2] + rs_[3];
  ss = rss_[0] + rss_[1] + rss_[2] + rss_[3];
  float mu = s * (1.f / 1024.f);
  float var = ss * (1.f / 1024.f) - mu * mu;
  float rstd = rsqrtf(var + 1e-5f);
  float4 gv = *(const float4*)(g + threadIdx.x * 4);
  float4 bv = *(const float4*)(b + threadIdx.x * 4);
  uint32_t lo = (uint32_t)f2bf((v.x - mu) * rstd * gv.x + bv.x) |
                ((uint32_t)f2bf((v.y - mu) * rstd * gv.y + bv.y) << 16);
  uint32_t hi = (uint32_t)f2bf((v.z - mu) * rstd * gv.z + bv.z) |
                ((uint32_t)f2bf((v.w - mu) * rstd * gv.w + bv.w) << 16);
  uint2 o; o.x = lo; o.y = hi;
  *(uint2*)(out + (size_t)row * 1024 + threadIdx.x * 4) = o;
}

// ---------------- GEMM (m97 structure): C = A(bf16 MxK) * BT(bf16 NxK) ----------------
#define BM 128
#define BN 128
#define BK 64

template <int MODE>
__global__ __launch_bounds__(256) void gemm_bt(
    const u16* __restrict__ A, const u16* __restrict__ BT,
    int M, int N, int K,
    const float* __restrict__ bias, const float* __restrict__ resid,
    float* __restrict__ outf,
    u16* __restrict__ ob0, u16* __restrict__ ob1, u16* __restrict__ ob2) {
  __shared__ u16 As[BM * BK];
  __shared__ u16 Bs[BN * BK];
  const int tid = threadIdx.x, lane = tid & 63;
  const int wr = (tid >> 6) >> 1, wc = (tid >> 6) & 1;
  const int bm = blockIdx.y, bn = blockIdx.x;
  const int l15 = lane & 15, lhi = lane >> 4;
  const int srow = tid >> 3, scol = (tid & 7) * 8;
  const int wv512 = (tid >> 6) * 512;

  f32x4 acc[4][4];
#pragma unroll
  for (int i = 0; i < 4; ++i)
#pragma unroll
    for (int j = 0; j < 4; ++j) acc[i][j] = (f32x4){0.f, 0.f, 0.f, 0.f};

  for (int kt = 0; kt < K; kt += BK) {
    __syncthreads();
#pragma unroll
    for (int c = 0; c < 4; ++c) {
      int row = c * 32 + srow;
      __builtin_amdgcn_global_load_lds(
          (gu32*)(A + (size_t)(bm * BM + row) * K + kt + scol),
          (lu32*)&As[c * 2048 + wv512], 16, 0, 0);
      __builtin_amdgcn_global_load_lds(
          (gu32*)(BT + (size_t)(bn * BN + row) * K + kt + scol),
          (lu32*)&Bs[c * 2048 + wv512], 16, 0, 0);
    }
    __syncthreads();
#pragma unroll
    for (int ks = 0; ks < 2; ++ks) {
      bf16x8 af[4], bf[4];
#pragma unroll
      for (int i = 0; i < 4; ++i)
        af[i] = *(const bf16x8*)&As[(wr * 64 + i * 16 + l15) * BK + ks * 32 + lhi * 8];
#pragma unroll
      for (int j = 0; j < 4; ++j)
        bf[j] = *(const bf16x8*)&Bs[(wc * 64 + j * 16 + l15) * BK + ks * 32 + lhi * 8];
#pragma unroll
      for (int i = 0; i < 4; ++i)
#pragma unroll
        for (int j = 0; j < 4; ++j)
          acc[i][j] = __builtin_amdgcn_mfma_f32_16x16x32_bf16(af[i], bf[j], acc[i][j], 0, 0, 0);
    }
  }

#pragma unroll
  for (int i = 0; i < 4; ++i) {
#pragma unroll
    for (int j = 0; j < 4; ++j) {
      int col = bn * BN + wc * 64 + j * 16 + l15;
      int rbase = bm * BM + wr * 64 + i * 16 + lhi * 4;
#pragma unroll
      for (int r = 0; r < 4; ++r) {
        float v = acc[i][j][r];
        int rg = rbase + r;
        if (MODE == 0) {
          int b = rg >> 11, t = rg & 2047;
          int cm = col & 1023, h = cm >> 6, d = cm & 63;
          size_t bh = (size_t)(b * 16 + h);
          if (col < 1024)
            ob0[(bh * 2048 + t) * 64 + d] = f2bf(v * 0.125f);
          else if (col < 2048)
            ob1[(bh * 2048 + t) * 64 + d] = f2bf(v);
          else
            ob2[(bh * 64 + d) * 2048 + t] = f2bf(v);
        } else if (MODE == 1) {
          outf[(size_t)rg * N + col] = v + bias[col] + resid[(size_t)rg * N + col];
        } else if (MODE == 2) {
          ob0[(size_t)rg * N + col] = f2bf(fmaxf(v + bias[col], 0.f));
        } else {
          outf[(size_t)rg * N + col] = fmaxf(v + bias[col], 0.f) + resid[(size_t)rg * N + col];
        }
      }
    }
  }
}

// ---------------- causal flash attention (balanced pairs, swapped QK^T, dbuf) ----------
// Block p handles q-tiles (7-p) then (p), 256 rows each; 8 waves x 32 rows.
// Q,K: [B*H, T, 64] bf16 (Q pre-scaled by 1/8); VT: [B*H, 64, T] bf16
// O: [B*T, 1024] bf16
__global__ __launch_bounds__(512) void attn_kernel(
    const u16* __restrict__ Qb, const u16* __restrict__ Kb,
    const u16* __restrict__ VTb, u16* __restrict__ O) {
  const int p = blockIdx.x;  // 0..3
  const int bh = blockIdx.y;
  const u16* Q = Qb + (size_t)bh * 2048 * 64;
  const u16* Kp = Kb + (size_t)bh * 2048 * 64;
  const u16* VT = VTb + (size_t)bh * 64 * 2048;
  const int tid = threadIdx.x, lane = tid & 63, wv = tid >> 6;
  const int l15 = lane & 15, lhi = lane >> 4;
  const int srow = tid >> 3, scol = (tid & 7) * 8;  // 512 thr x 8 elems = 64x64 tile
  const int b = bh >> 4, h = bh & 15;

  __shared__ u16 Ks[2][64 * 72];
  __shared__ u16 Vs[2][64 * 72];
  __shared__ u16 Ps[8][32 * 72];

#pragma unroll
  for (int pass = 0; pass < 2; ++pass) {
    const int qtile = (pass == 0) ? (7 - p) : p;
    const int qbase = qtile * 256 + wv * 32;
    const int nkt = qtile * 4 + 4;

    bf16x8 qf[2][2];
#pragma unroll
    for (int rf = 0; rf < 2; ++rf)
#pragma unroll
      for (int ks = 0; ks < 2; ++ks)
        qf[rf][ks] = *(const bf16x8*)&Q[(size_t)(qbase + rf * 16 + l15) * 64 + ks * 32 + lhi * 8];

    f32x4 o[2][4];
#pragma unroll
    for (int rf = 0; rf < 2; ++rf)
#pragma unroll
      for (int f = 0; f < 4; ++f) o[rf][f] = (f32x4){0.f, 0.f, 0.f, 0.f};
    float m[2] = {-1e30f, -1e30f};
    float l[2] = {0.f, 0.f};

    // prologue: stage tile 0 into buffer 0
    {
      bf16x8 kreg = *(const bf16x8*)&Kp[(size_t)srow * 64 + scol];
      bf16x8 vreg = *(const bf16x8*)&VT[(size_t)srow * 2048 + scol];
      __syncthreads();  // previous pass's reads of LDS complete
      *(bf16x8*)&Ks[0][srow * 72 + scol] = kreg;
      *(bf16x8*)&Vs[0][srow * 72 + scol] = vreg;
    }

    for (int kt = 0; kt < nkt; ++kt) {
      const int cur = kt & 1;
      __syncthreads();  // LDS[cur] visible; prior reads of LDS[cur^1] done

      // issue next tile's global loads (latency hides under compute)
      bf16x8 kreg, vreg;
      const bool haveNext = (kt + 1 < nkt);
      if (haveNext) {
        kreg = *(const bf16x8*)&Kp[((size_t)(kt + 1) * 64 + srow) * 64 + scol];
        vreg = *(const bf16x8*)&VT[(size_t)srow * 2048 + (kt + 1) * 64 + scol];
      }

      if (kt * 64 <= qbase + 31) {  // wave has unmasked rows in this tile
        // ---- QK^T swapped: s[rf][jt] holds S[q = qbase+rf*16+l15, k = kt*64+jt*16+lhi*4+r]
        f32x4 s[2][4];
#pragma unroll
        for (int rf = 0; rf < 2; ++rf)
#pragma unroll
          for (int jt = 0; jt < 4; ++jt) s[rf][jt] = (f32x4){0.f, 0.f, 0.f, 0.f};
#pragma unroll
        for (int ks = 0; ks < 2; ++ks)
#pragma unroll
          for (int jt = 0; jt < 4; ++jt) {
            bf16x8 kf = *(const bf16x8*)&Ks[cur][(jt * 16 + l15) * 72 + ks * 32 + lhi * 8];
            s[0][jt] = __builtin_amdgcn_mfma_f32_16x16x32_bf16(kf, qf[0][ks], s[0][jt], 0, 0, 0);
            s[1][jt] = __builtin_amdgcn_mfma_f32_16x16x32_bf16(kf, qf[1][ks], s[1][jt], 0, 0, 0);
          }

        if (kt * 64 + 63 > qbase) {  // diagonal-crossing: causal mask
#pragma unroll
          for (int rf = 0; rf < 2; ++rf) {
            int qg = qbase + rf * 16 + l15;
#pragma unroll
            for (int jt = 0; jt < 4; ++jt)
#pragma unroll
              for (int r = 0; r < 4; ++r) {
                int kg = kt * 64 + jt * 16 + lhi * 4 + r;
                if (kg > qg) s[rf][jt][r] = -1e30f;
              }
          }
        }

        // ---- online softmax: row is lane-local across 16 regs + 4-lane group
        float sc[2];
#pragma unroll
        for (int rf = 0; rf < 2; ++rf) {
          float mr = s[rf][0][0];
#pragma unroll
          for (int jt = 0; jt < 4; ++jt)
#pragma unroll
            for (int r = 0; r < 4; ++r) mr = fmaxf(mr, s[rf][jt][r]);
          mr = fmaxf(mr, __shfl_xor(mr, 16));
          mr = fmaxf(mr, __shfl_xor(mr, 32));
          float mn = fmaxf(m[rf], mr);
          sc[rf] = exp2f((m[rf] - mn) * LOG2E);
          float rs = 0.f;
#pragma unroll
          for (int jt = 0; jt < 4; ++jt)
#pragma unroll
            for (int r = 0; r < 4; ++r) {
              float pv = exp2f((s[rf][jt][r] - mn) * LOG2E);
              s[rf][jt][r] = pv;
              rs += pv;
            }
          rs += __shfl_xor(rs, 16);
          rs += __shfl_xor(rs, 32);
          l[rf] = l[rf] * sc[rf] + rs;
          m[rf] = mn;
        }

        // rescale o (o rows live at q = qbase+rf*16+lhi*4+r -> fetch sc from lane lhi*4+r)
#pragma unroll
        for (int rf = 0; rf < 2; ++rf)
#pragma unroll
          for (int r = 0; r < 4; ++r) {
            float so = __shfl(sc[rf], lhi * 4 + r);
#pragma unroll
            for (int f = 0; f < 4; ++f) o[rf][f][r] *= so;
          }

        // ---- P -> LDS (vectorized b64 per jt), then PV
#pragma unroll
        for (int rf = 0; rf < 2; ++rf)
#pragma unroll
          for (int jt = 0; jt < 4; ++jt) {
            u16x4 pk;
#pragma unroll
            for (int r = 0; r < 4; ++r) pk[r] = f2bf(s[rf][jt][r]);
            *(u16x4*)&Ps[wv][(rf * 16 + l15) * 72 + jt * 16 + lhi * 4] = pk;
          }
        // Ps is wave-private: lgkmcnt dependency handled by compiler, no barrier
#pragma unroll
        for (int ks = 0; ks < 2; ++ks) {
          bf16x8 pf0 = *(const bf16x8*)&Ps[wv][(l15)*72 + ks * 32 + lhi * 8];
          bf16x8 pf1 = *(const bf16x8*)&Ps[wv][(16 + l15) * 72 + ks * 32 + lhi * 8];
#pragma unroll
          for (int f = 0; f < 4; ++f) {
            bf16x8 vfr = *(const bf16x8*)&Vs[cur][(f * 16 + l15) * 72 + ks * 32 + lhi * 8];
            o[0][f] = __builtin_amdgcn_mfma_f32_16x16x32_bf16(pf0, vfr, o[0][f], 0, 0, 0);
            o[1][f] = __builtin_amdgcn_mfma_f32_16x16x32_bf16(pf1, vfr, o[1][f], 0, 0, 0);
          }
        }
      }

      // write next tile into the other buffer (all threads, even masked waves)
      if (haveNext) {
        *(bf16x8*)&Ks[cur ^ 1][srow * 72 + scol] = kreg;
        *(bf16x8*)&Vs[cur ^ 1][srow * 72 + scol] = vreg;
      }
    }

    // ---- epilogue: denominators to o-layout, write O
#pragma unroll
    for (int rf = 0; rf < 2; ++rf)
#pragma unroll
      for (int r = 0; r < 4; ++r) {
        float ld = __shfl(l[rf], lhi * 4 + r);
        float inv = 1.f / ld;
        int t = qbase + rf * 16 + lhi * 4 + r;
#pragma unroll
        for (int f = 0; f < 4; ++f)
          O[((size_t)(b * 2048 + t)) * 1024 + h * 64 + f * 16 + l15] = f2bf(o[rf][f][r] * inv);
      }
  }
}

extern "C" void kernel_launch(void* const* d_in, const int* in_sizes, int n_in,
                              void* d_out, int out_size, void* d_ws, size_t ws_size,
                              hipStream_t stream) {
  const float* x   = (const float*)d_in[0];
  const float* Wq  = (const float*)d_in[1];
  const float* Wk  = (const float*)d_in[2];
  const float* Wv  = (const float*)d_in[3];
  const float* Wo  = (const float*)d_in[4];
  const float* bo  = (const float*)d_in[5];
  const float* W1  = (const float*)d_in[6];
  const float* b1  = (const float*)d_in[7];
  const float* W2  = (const float*)d_in[8];
  const float* b2  = (const float*)d_in[9];
  const float* g1  = (const float*)d_in[10];
  const float* be1 = (const float*)d_in[11];
  const float* g2  = (const float*)d_in[12];
  const float* be2 = (const float*)d_in[13];

  char* p = (char*)d_ws;
  auto alloc = [&](size_t bytes) {
    char* r = p;
    p += (bytes + 255) & ~(size_t)255;
    return r;
  };
  u16* WqkvT = (u16*)alloc(3072ull * 1024 * 2);
  u16* WoT   = (u16*)alloc(1024ull * 1024 * 2);
  u16* W1T   = (u16*)alloc(4096ull * 1024 * 2);
  u16* W2T   = (u16*)alloc(1024ull * 4096 * 2);
  u16* hln   = (u16*)alloc(8192ull * 1024 * 2);
  u16* Qbuf  = (u16*)alloc(8192ull * 1024 * 2);
  u16* Kbuf  = (u16*)alloc(8192ull * 1024 * 2);
  u16* VTbuf = (u16*)alloc(8192ull * 1024 * 2);
  float* x2  = (float*)alloc(8192ull * 1024 * 4);
  u16* ff1   = (u16*)alloc(8192ull * 4096 * 2);
  u16* Oattn = hln;   // hln dead after QKV GEMM
  u16* h2    = Qbuf;  // Qbuf dead after attention
  if ((size_t)(p - (char*)d_ws) > ws_size) return;  // ws too small: bail

  dim3 tb(32, 8);
  transpose_w<<<dim3(32, 32), tb, 0, stream>>>(Wq, WqkvT, 1024, 1024);
  transpose_w<<<dim3(32, 32), tb, 0, stream>>>(Wk, WqkvT + 1024 * 1024, 1024, 1024);
  transpose_w<<<dim3(32, 32), tb, 0, stream>>>(Wv, WqkvT + 2048 * 1024, 1024, 1024);
  transpose_w<<<dim3(32, 32), tb, 0, stream>>>(Wo, WoT, 1024, 1024);
  transpose_w<<<dim3(128, 32), tb, 0, stream>>>(W1, W1T, 1024, 4096);
  transpose_w<<<dim3(32, 128), tb, 0, stream>>>(W2, W2T, 4096, 1024);

  ln_kernel<<<8192, 256, 0, stream>>>(x, g1, be1, hln);

  gemm_bt<0><<<dim3(24, 64), 256, 0, stream>>>(hln, WqkvT, 8192, 3072, 1024,
                                               nullptr, nullptr, nullptr,
                                               Qbuf, Kbuf, VTbuf);

  attn_kernel<<<dim3(4, 64), 512, 0, stream>>>(Qbuf, Kbuf, VTbuf, Oattn);

  gemm_bt<1><<<dim3(8, 64), 256, 0, stream>>>(Oattn, WoT, 8192, 1024, 1024,
                                              bo, x, x2, nullptr, nullptr, nullptr);

  ln_kernel<<<8192, 256, 0, stream>>>(x2, g2, be2, h2);

  gemm_bt<2><<<dim3(32, 64), 256, 0, stream>>>(h2, W1T, 8192, 4096, 1024,
                                               b1, nullptr, nullptr, ff1, nullptr, nullptr);

  gemm_bt<3><<<dim3(8, 64), 256, 0, stream>>>(ff1, W2T, 8192, 1024, 4096,
                                              b2, x2, (float*)d_out, nullptr, nullptr, nullptr);
}

// Round 4
// 454.952 us; speedup vs baseline: 1.3900x; 1.0812x over previous
//
#include <hip/hip_runtime.h>
#include <cstdint>
#include <cstddef>

typedef unsigned short u16;
typedef __attribute__((ext_vector_type(8))) short bf16x8;
typedef __attribute__((ext_vector_type(4))) float f32x4;
typedef __attribute__((ext_vector_type(4))) u16 u16x4;
typedef __attribute__((address_space(1))) const unsigned int gu32;
typedef __attribute__((address_space(3))) unsigned int lu32;

#define LOG2E 1.44269504088896340736f

__device__ __forceinline__ u16 f2bf(float f) {
  uint32_t u = __float_as_uint(f);
  u += 0x7fffu + ((u >> 16) & 1u);
  return (u16)(u >> 16);
}

// ---------------- transpose fp32 (K,N) -> bf16 (N,K) ----------------
__global__ __launch_bounds__(256) void transpose_w(const float* __restrict__ W,
                                                   u16* __restrict__ WT,
                                                   int K, int N) {
  __shared__ float t[32][33];
  int n0 = blockIdx.x * 32, k0 = blockIdx.y * 32;
  for (int i = threadIdx.y; i < 32; i += 8)
    t[i][threadIdx.x] = W[(size_t)(k0 + i) * N + n0 + threadIdx.x];
  __syncthreads();
  for (int i = threadIdx.y; i < 32; i += 8)
    WT[(size_t)(n0 + i) * K + k0 + threadIdx.x] = f2bf(t[threadIdx.x][i]);
}

// ---------------- layernorm fp32 row(1024) -> bf16 ----------------
__global__ __launch_bounds__(256) void ln_kernel(const float* __restrict__ x,
                                                 const float* __restrict__ g,
                                                 const float* __restrict__ b,
                                                 u16* __restrict__ out) {
  int row = blockIdx.x;
  const float4 v = *(const float4*)(x + (size_t)row * 1024 + threadIdx.x * 4);
  float s = v.x + v.y + v.z + v.w;
  float ss = v.x * v.x + v.y * v.y + v.z * v.z + v.w * v.w;
#pragma unroll
  for (int d = 1; d < 64; d <<= 1) { s += __shfl_xor(s, d); ss += __shfl_xor(ss, d); }
  __shared__ float rs_[4], rss_[4];
  int wv = threadIdx.x >> 6;
  if ((threadIdx.x & 63) == 0) { rs_[wv] = s; rss_[wv] = ss; }
  __syncthreads();
  s = rs_[0] + rs_[1] + rs_[2] + rs_[3];
  ss = rss_[0] + rss_[1] + rss_[2] + rss_[3];
  float mu = s * (1.f / 1024.f);
  float var = ss * (1.f / 1024.f) - mu * mu;
  float rstd = rsqrtf(var + 1e-5f);
  float4 gv = *(const float4*)(g + threadIdx.x * 4);
  float4 bv = *(const float4*)(b + threadIdx.x * 4);
  uint32_t lo = (uint32_t)f2bf((v.x - mu) * rstd * gv.x + bv.x) |
                ((uint32_t)f2bf((v.y - mu) * rstd * gv.y + bv.y) << 16);
  uint32_t hi = (uint32_t)f2bf((v.z - mu) * rstd * gv.z + bv.z) |
                ((uint32_t)f2bf((v.w - mu) * rstd * gv.w + bv.w) << 16);
  uint2 o; o.x = lo; o.y = hi;
  *(uint2*)(out + (size_t)row * 1024 + threadIdx.x * 4) = o;
}

// ---------------- deep-pipelined GEMM: C = A(bf16 MxK) * BT(bf16 NxK) ----------------
// BM=256 BN=128 BK=64, 8 waves (4Mx2N), ring-3 LDS (144KB), prefetch 2 K-tiles ahead,
// counted vmcnt (6 steady), 2 phases/K-tile of 16 MFMA, T2 row-XOR swizzle, T5 setprio.
// MODE 0: QKV  (N=3072) -> Q[B,H,T,HD]*0.125 / K[B,H,T,HD] / VT[B,H,HD,T]
// MODE 1: PROJ -> outf = acc + bias + resid      (fp32)
// MODE 2: FF1  -> ob0  = bf16(relu(acc + bias))
// MODE 3: FF2  -> outf = relu(acc + bias) + resid (fp32)

#define STAGEA(slot, tnext, is)                                               \
  __builtin_amdgcn_global_load_lds(                                           \
      (gu32*)((const char*)(A + (size_t)(bm * 256 + (is) * 64 + srow) * K +   \
                            (size_t)(tnext) * 64) + ssw),                     \
      (lu32*)&lds[(slot) * 24576 + (is) * 4096 + wid * 512], 16, 0, 0)
#define STAGEB(slot, tnext, is)                                               \
  __builtin_amdgcn_global_load_lds(                                           \
      (gu32*)((const char*)(BT + (size_t)(bn * 128 + (is) * 64 + srow) * K +  \
                            (size_t)(tnext) * 64) + ssw),                     \
      (lu32*)&lds[(slot) * 24576 + 16384 + (is) * 4096 + wid * 512], 16, 0, 0)

template <int MODE>
__global__ __launch_bounds__(512, 2) void gemm8p(
    const u16* __restrict__ A, const u16* __restrict__ BT,
    int M, int N, int K,
    const float* __restrict__ bias, const float* __restrict__ resid,
    float* __restrict__ outf,
    u16* __restrict__ ob0, u16* __restrict__ ob1, u16* __restrict__ ob2) {
  __shared__ __align__(16) u16 lds[73728];  // 3 x (A 256x64 + B 128x64) = 144 KB
  const int tid = threadIdx.x, lane = tid & 63, wid = tid >> 6;
  const int wr = wid >> 1, wc = wid & 1;  // 4 x 2 wave grid; wave tile 64x64
  const int bm = blockIdx.y, bn = blockIdx.x;
  const int l15 = lane & 15, lhi = lane >> 4;
  const int srow = tid >> 3;                                  // staging row (0..63)
  const int ssw = ((tid & 7) * 16) ^ ((srow & 7) << 4);       // inverse-swizzled src byte
  const int cs0 = (lhi * 8) ^ ((l15 & 7) << 3);               // swizzled read col, ks=0
  const int cs1 = (32 + lhi * 8) ^ ((l15 & 7) << 3);          // ks=1
  const int arow = (wr * 64 + l15) * 64;                      // elem base in A panel
  const int brow = (wc * 64 + l15) * 64;                      // elem base in B panel

  f32x4 acc[4][4];
#pragma unroll
  for (int i = 0; i < 4; ++i)
#pragma unroll
    for (int j = 0; j < 4; ++j) acc[i][j] = (f32x4){0.f, 0.f, 0.f, 0.f};

  const int NT = K >> 6;  // >= 16 for all our shapes

  // prologue: stage tiles 0,1,2 into slots 0,1,2 (18 loads/thread)
#pragma unroll
  for (int t0 = 0; t0 < 3; ++t0) {
    STAGEA(t0, t0, 0); STAGEA(t0, t0, 1); STAGEA(t0, t0, 2); STAGEA(t0, t0, 3);
    STAGEB(t0, t0, 0); STAGEB(t0, t0, 1);
  }
  asm volatile("s_waitcnt vmcnt(12)" ::: "memory");  // tile 0 landed
  __builtin_amdgcn_s_barrier();

  int s = 0, sn = 2;  // compute slot, prefetch slot (t+2)%3
  for (int t = 0; t < NT; ++t) {
    const bool hasPre = (t + 2) < NT;
    const int aoff = s * 24576, boff = s * 24576 + 16384;

    // ---------- phase 0: B frags + A frags (mi 0,1); stage 3 ----------
    bf16x8 bfr[4][2], afr[2][2];
#pragma unroll
    for (int ni = 0; ni < 4; ++ni) {
      bfr[ni][0] = *(const bf16x8*)&lds[boff + brow + ni * 1024 + cs0];
      bfr[ni][1] = *(const bf16x8*)&lds[boff + brow + ni * 1024 + cs1];
    }
    afr[0][0] = *(const bf16x8*)&lds[aoff + arow + cs0];
    afr[0][1] = *(const bf16x8*)&lds[aoff + arow + cs1];
    afr[1][0] = *(const bf16x8*)&lds[aoff + arow + 1024 + cs0];
    afr[1][1] = *(const bf16x8*)&lds[aoff + arow + 1024 + cs1];
    if (hasPre) { STAGEA(sn, t + 2, 0); STAGEA(sn, t + 2, 1); STAGEB(sn, t + 2, 0); }
    __builtin_amdgcn_s_barrier();
    __builtin_amdgcn_s_setprio(1);
#pragma unroll
    for (int ml = 0; ml < 2; ++ml)
#pragma unroll
      for (int ni = 0; ni < 4; ++ni) {
        acc[ml][ni] = __builtin_amdgcn_mfma_f32_16x16x32_bf16(afr[ml][0], bfr[ni][0], acc[ml][ni], 0, 0, 0);
        acc[ml][ni] = __builtin_amdgcn_mfma_f32_16x16x32_bf16(afr[ml][1], bfr[ni][1], acc[ml][ni], 0, 0, 0);
      }
    __builtin_amdgcn_s_setprio(0);
    __builtin_amdgcn_s_barrier();

    // ---------- phase 1: A frags (mi 2,3); stage 3; end-of-tile vmcnt ----------
    afr[0][0] = *(const bf16x8*)&lds[aoff + arow + 2048 + cs0];
    afr[0][1] = *(const bf16x8*)&lds[aoff + arow + 2048 + cs1];
    afr[1][0] = *(const bf16x8*)&lds[aoff + arow + 3072 + cs0];
    afr[1][1] = *(const bf16x8*)&lds[aoff + arow + 3072 + cs1];
    if (hasPre) { STAGEA(sn, t + 2, 2); STAGEA(sn, t + 2, 3); STAGEB(sn, t + 2, 1); }
    __builtin_amdgcn_s_barrier();
    __builtin_amdgcn_s_setprio(1);
#pragma unroll
    for (int ml = 0; ml < 2; ++ml)
#pragma unroll
      for (int ni = 0; ni < 4; ++ni) {
        acc[2 + ml][ni] = __builtin_amdgcn_mfma_f32_16x16x32_bf16(afr[ml][0], bfr[ni][0], acc[2 + ml][ni], 0, 0, 0);
        acc[2 + ml][ni] = __builtin_amdgcn_mfma_f32_16x16x32_bf16(afr[ml][1], bfr[ni][1], acc[2 + ml][ni], 0, 0, 0);
      }
    __builtin_amdgcn_s_setprio(0);
    if (hasPre) {
      asm volatile("s_waitcnt vmcnt(6)" ::: "memory");   // tile t+1 landed, t+2 in flight
    } else if (t + 1 < NT) {
      asm volatile("s_waitcnt vmcnt(0)" ::: "memory");   // tail drain
    }
    __builtin_amdgcn_s_barrier();

    s = (s == 2) ? 0 : s + 1;
    sn = (sn == 2) ? 0 : sn + 1;
  }

  // ---------------- epilogue ----------------
#pragma unroll
  for (int mi = 0; mi < 4; ++mi) {
#pragma unroll
    for (int ni = 0; ni < 4; ++ni) {
      int col = bn * 128 + wc * 64 + ni * 16 + l15;
      int rbase = bm * 256 + wr * 64 + mi * 16 + lhi * 4;
#pragma unroll
      for (int r = 0; r < 4; ++r) {
        float v = acc[mi][ni][r];
        int rg = rbase + r;
        if (MODE == 0) {
          int b = rg >> 11, tt = rg & 2047;
          int cm = col & 1023, h = cm >> 6, d = cm & 63;
          size_t bh = (size_t)(b * 16 + h);
          if (col < 1024)
            ob0[(bh * 2048 + tt) * 64 + d] = f2bf(v * 0.125f);
          else if (col < 2048)
            ob1[(bh * 2048 + tt) * 64 + d] = f2bf(v);
          else
            ob2[(bh * 64 + d) * 2048 + tt] = f2bf(v);
        } else if (MODE == 1) {
          outf[(size_t)rg * N + col] = v + bias[col] + resid[(size_t)rg * N + col];
        } else if (MODE == 2) {
          ob0[(size_t)rg * N + col] = f2bf(fmaxf(v + bias[col], 0.f));
        } else {
          outf[(size_t)rg * N + col] = fmaxf(v + bias[col], 0.f) + resid[(size_t)rg * N + col];
        }
      }
    }
  }
}

// ---------------- causal flash attention (balanced pairs, swapped QK^T, dbuf) ----------
__global__ __launch_bounds__(512) void attn_kernel(
    const u16* __restrict__ Qb, const u16* __restrict__ Kb,
    const u16* __restrict__ VTb, u16* __restrict__ O) {
  const int p = blockIdx.x;  // 0..3
  const int bh = blockIdx.y;
  const u16* Q = Qb + (size_t)bh * 2048 * 64;
  const u16* Kp = Kb + (size_t)bh * 2048 * 64;
  const u16* VT = VTb + (size_t)bh * 64 * 2048;
  const int tid = threadIdx.x, lane = tid & 63, wv = tid >> 6;
  const int l15 = lane & 15, lhi = lane >> 4;
  const int srow = tid >> 3, scol = (tid & 7) * 8;
  const int b = bh >> 4, h = bh & 15;

  __shared__ u16 Ks[2][64 * 72];
  __shared__ u16 Vs[2][64 * 72];
  __shared__ u16 Ps[8][32 * 72];

#pragma unroll
  for (int pass = 0; pass < 2; ++pass) {
    const int qtile = (pass == 0) ? (7 - p) : p;
    const int qbase = qtile * 256 + wv * 32;
    const int nkt = qtile * 4 + 4;

    bf16x8 qf[2][2];
#pragma unroll
    for (int rf = 0; rf < 2; ++rf)
#pragma unroll
      for (int ks = 0; ks < 2; ++ks)
        qf[rf][ks] = *(const bf16x8*)&Q[(size_t)(qbase + rf * 16 + l15) * 64 + ks * 32 + lhi * 8];

    f32x4 o[2][4];
#pragma unroll
    for (int rf = 0; rf < 2; ++rf)
#pragma unroll
      for (int f = 0; f < 4; ++f) o[rf][f] = (f32x4){0.f, 0.f, 0.f, 0.f};
    float m[2] = {-1e30f, -1e30f};
    float l[2] = {0.f, 0.f};

    {
      bf16x8 kreg = *(const bf16x8*)&Kp[(size_t)srow * 64 + scol];
      bf16x8 vreg = *(const bf16x8*)&VT[(size_t)srow * 2048 + scol];
      __syncthreads();
      *(bf16x8*)&Ks[0][srow * 72 + scol] = kreg;
      *(bf16x8*)&Vs[0][srow * 72 + scol] = vreg;
    }

    for (int kt = 0; kt < nkt; ++kt) {
      const int cur = kt & 1;
      __syncthreads();

      bf16x8 kreg, vreg;
      const bool haveNext = (kt + 1 < nkt);
      if (haveNext) {
        kreg = *(const bf16x8*)&Kp[((size_t)(kt + 1) * 64 + srow) * 64 + scol];
        vreg = *(const bf16x8*)&VT[(size_t)srow * 2048 + (kt + 1) * 64 + scol];
      }

      if (kt * 64 <= qbase + 31) {
        f32x4 s[2][4];
#pragma unroll
        for (int rf = 0; rf < 2; ++rf)
#pragma unroll
          for (int jt = 0; jt < 4; ++jt) s[rf][jt] = (f32x4){0.f, 0.f, 0.f, 0.f};
#pragma unroll
        for (int ks = 0; ks < 2; ++ks)
#pragma unroll
          for (int jt = 0; jt < 4; ++jt) {
            bf16x8 kf = *(const bf16x8*)&Ks[cur][(jt * 16 + l15) * 72 + ks * 32 + lhi * 8];
            s[0][jt] = __builtin_amdgcn_mfma_f32_16x16x32_bf16(kf, qf[0][ks], s[0][jt], 0, 0, 0);
            s[1][jt] = __builtin_amdgcn_mfma_f32_16x16x32_bf16(kf, qf[1][ks], s[1][jt], 0, 0, 0);
          }

        if (kt * 64 + 63 > qbase) {
#pragma unroll
          for (int rf = 0; rf < 2; ++rf) {
            int qg = qbase + rf * 16 + l15;
#pragma unroll
            for (int jt = 0; jt < 4; ++jt)
#pragma unroll
              for (int r = 0; r < 4; ++r) {
                int kg = kt * 64 + jt * 16 + lhi * 4 + r;
                if (kg > qg) s[rf][jt][r] = -1e30f;
              }
          }
        }

        float sc[2];
#pragma unroll
        for (int rf = 0; rf < 2; ++rf) {
          float mr = s[rf][0][0];
#pragma unroll
          for (int jt = 0; jt < 4; ++jt)
#pragma unroll
            for (int r = 0; r < 4; ++r) mr = fmaxf(mr, s[rf][jt][r]);
          mr = fmaxf(mr, __shfl_xor(mr, 16));
          mr = fmaxf(mr, __shfl_xor(mr, 32));
          float mn = fmaxf(m[rf], mr);
          sc[rf] = exp2f((m[rf] - mn) * LOG2E);
          float rs = 0.f;
#pragma unroll
          for (int jt = 0; jt < 4; ++jt)
#pragma unroll
            for (int r = 0; r < 4; ++r) {
              float pv = exp2f((s[rf][jt][r] - mn) * LOG2E);
              s[rf][jt][r] = pv;
              rs += pv;
            }
          rs += __shfl_xor(rs, 16);
          rs += __shfl_xor(rs, 32);
          l[rf] = l[rf] * sc[rf] + rs;
          m[rf] = mn;
        }

#pragma unroll
        for (int rf = 0; rf < 2; ++rf)
#pragma unroll
          for (int r = 0; r < 4; ++r) {
            float so = __shfl(sc[rf], lhi * 4 + r);
#pragma unroll
            for (int f = 0; f < 4; ++f) o[rf][f][r] *= so;
          }

#pragma unroll
        for (int rf = 0; rf < 2; ++rf)
#pragma unroll
          for (int jt = 0; jt < 4; ++jt) {
            u16x4 pk;
#pragma unroll
            for (int r = 0; r < 4; ++r) pk[r] = f2bf(s[rf][jt][r]);
            *(u16x4*)&Ps[wv][(rf * 16 + l15) * 72 + jt * 16 + lhi * 4] = pk;
          }
#pragma unroll
        for (int ks = 0; ks < 2; ++ks) {
          bf16x8 pf0 = *(const bf16x8*)&Ps[wv][(l15)*72 + ks * 32 + lhi * 8];
          bf16x8 pf1 = *(const bf16x8*)&Ps[wv][(16 + l15) * 72 + ks * 32 + lhi * 8];
#pragma unroll
          for (int f = 0; f < 4; ++f) {
            bf16x8 vfr = *(const bf16x8*)&Vs[cur][(f * 16 + l15) * 72 + ks * 32 + lhi * 8];
            o[0][f] = __builtin_amdgcn_mfma_f32_16x16x32_bf16(pf0, vfr, o[0][f], 0, 0, 0);
            o[1][f] = __builtin_amdgcn_mfma_f32_16x16x32_bf16(pf1, vfr, o[1][f], 0, 0, 0);
          }
        }
      }

      if (haveNext) {
        *(bf16x8*)&Ks[cur ^ 1][srow * 72 + scol] = kreg;
        *(bf16x8*)&Vs[cur ^ 1][srow * 72 + scol] = vreg;
      }
    }

#pragma unroll
    for (int rf = 0; rf < 2; ++rf)
#pragma unroll
      for (int r = 0; r < 4; ++r) {
        float ld = __shfl(l[rf], lhi * 4 + r);
        float inv = 1.f / ld;
        int t = qbase + rf * 16 + lhi * 4 + r;
#pragma unroll
        for (int f = 0; f < 4; ++f)
          O[((size_t)(b * 2048 + t)) * 1024 + h * 64 + f * 16 + l15] = f2bf(o[rf][f][r] * inv);
      }
  }
}

extern "C" void kernel_launch(void* const* d_in, const int* in_sizes, int n_in,
                              void* d_out, int out_size, void* d_ws, size_t ws_size,
                              hipStream_t stream) {
  const float* x   = (const float*)d_in[0];
  const float* Wq  = (const float*)d_in[1];
  const float* Wk  = (const float*)d_in[2];
  const float* Wv  = (const float*)d_in[3];
  const float* Wo  = (const float*)d_in[4];
  const float* bo  = (const float*)d_in[5];
  const float* W1  = (const float*)d_in[6];
  const float* b1  = (const float*)d_in[7];
  const float* W2  = (const float*)d_in[8];
  const float* b2  = (const float*)d_in[9];
  const float* g1  = (const float*)d_in[10];
  const float* be1 = (const float*)d_in[11];
  const float* g2  = (const float*)d_in[12];
  const float* be2 = (const float*)d_in[13];

  char* p = (char*)d_ws;
  auto alloc = [&](size_t bytes) {
    char* r = p;
    p += (bytes + 255) & ~(size_t)255;
    return r;
  };
  u16* WqkvT = (u16*)alloc(3072ull * 1024 * 2);
  u16* WoT   = (u16*)alloc(1024ull * 1024 * 2);
  u16* W1T   = (u16*)alloc(4096ull * 1024 * 2);
  u16* W2T   = (u16*)alloc(1024ull * 4096 * 2);
  u16* hln   = (u16*)alloc(8192ull * 1024 * 2);
  u16* Qbuf  = (u16*)alloc(8192ull * 1024 * 2);
  u16* Kbuf  = (u16*)alloc(8192ull * 1024 * 2);
  u16* VTbuf = (u16*)alloc(8192ull * 1024 * 2);
  float* x2  = (float*)alloc(8192ull * 1024 * 4);
  u16* ff1   = (u16*)alloc(8192ull * 4096 * 2);
  u16* Oattn = hln;   // hln dead after QKV GEMM
  u16* h2    = Qbuf;  // Qbuf dead after attention
  if ((size_t)(p - (char*)d_ws) > ws_size) return;

  dim3 tb(32, 8);
  transpose_w<<<dim3(32, 32), tb, 0, stream>>>(Wq, WqkvT, 1024, 1024);
  transpose_w<<<dim3(32, 32), tb, 0, stream>>>(Wk, WqkvT + 1024 * 1024, 1024, 1024);
  transpose_w<<<dim3(32, 32), tb, 0, stream>>>(Wv, WqkvT + 2048 * 1024, 1024, 1024);
  transpose_w<<<dim3(32, 32), tb, 0, stream>>>(Wo, WoT, 1024, 1024);
  transpose_w<<<dim3(128, 32), tb, 0, stream>>>(W1, W1T, 1024, 4096);
  transpose_w<<<dim3(32, 128), tb, 0, stream>>>(W2, W2T, 4096, 1024);

  ln_kernel<<<8192, 256, 0, stream>>>(x, g1, be1, hln);

  gemm8p<0><<<dim3(24, 32), 512, 0, stream>>>(hln, WqkvT, 8192, 3072, 1024,
                                              nullptr, nullptr, nullptr,
                                              Qbuf, Kbuf, VTbuf);

  attn_kernel<<<dim3(4, 64), 512, 0, stream>>>(Qbuf, Kbuf, VTbuf, Oattn);

  gemm8p<1><<<dim3(8, 32), 512, 0, stream>>>(Oattn, WoT, 8192, 1024, 1024,
                                             bo, x, x2, nullptr, nullptr, nullptr);

  ln_kernel<<<8192, 256, 0, stream>>>(x2, g2, be2, h2);

  gemm8p<2><<<dim3(32, 32), 512, 0, stream>>>(h2, W1T, 8192, 4096, 1024,
                                              b1, nullptr, nullptr, ff1, nullptr, nullptr);

  gemm8p<3><<<dim3(8, 32), 512, 0, stream>>>(ff1, W2T, 8192, 1024, 4096,
                                             b2, x2, (float*)d_out, nullptr, nullptr, nullptr);
}

// Round 5
// 444.753 us; speedup vs baseline: 1.4219x; 1.0229x over previous
//
#include <hip/hip_runtime.h>
#include <cstdint>
#include <cstddef>

typedef unsigned short u16;
typedef __attribute__((ext_vector_type(8))) short bf16x8;
typedef __attribute__((ext_vector_type(4))) float f32x4;
typedef __attribute__((ext_vector_type(4))) u16 u16x4;
typedef __attribute__((address_space(1))) const unsigned int gu32;
typedef __attribute__((address_space(3))) unsigned int lu32;

#define QSCALE 0.1803368801111204f  // 0.125 * log2(e): softmax done in exp2 domain

__device__ __forceinline__ u16 f2bf(float f) {
  uint32_t u = __float_as_uint(f);
  u += 0x7fffu + ((u >> 16) & 1u);
  return (u16)(u >> 16);
}

// ---------------- transpose fp32 (K,N) -> bf16 (N,K) ----------------
__global__ __launch_bounds__(256) void transpose_w(const float* __restrict__ W,
                                                   u16* __restrict__ WT,
                                                   int K, int N) {
  __shared__ float t[32][33];
  int n0 = blockIdx.x * 32, k0 = blockIdx.y * 32;
  for (int i = threadIdx.y; i < 32; i += 8)
    t[i][threadIdx.x] = W[(size_t)(k0 + i) * N + n0 + threadIdx.x];
  __syncthreads();
  for (int i = threadIdx.y; i < 32; i += 8)
    WT[(size_t)(n0 + i) * K + k0 + threadIdx.x] = f2bf(t[threadIdx.x][i]);
}

// ---------------- layernorm fp32 row(1024) -> bf16 ----------------
__global__ __launch_bounds__(256) void ln_kernel(const float* __restrict__ x,
                                                 const float* __restrict__ g,
                                                 const float* __restrict__ b,
                                                 u16* __restrict__ out) {
  int row = blockIdx.x;
  const float4 v = *(const float4*)(x + (size_t)row * 1024 + threadIdx.x * 4);
  float s = v.x + v.y + v.z + v.w;
  float ss = v.x * v.x + v.y * v.y + v.z * v.z + v.w * v.w;
#pragma unroll
  for (int d = 1; d < 64; d <<= 1) { s += __shfl_xor(s, d); ss += __shfl_xor(ss, d); }
  __shared__ float rs_[4], rss_[4];
  int wv = threadIdx.x >> 6;
  if ((threadIdx.x & 63) == 0) { rs_[wv] = s; rss_[wv] = ss; }
  __syncthreads();
  s = rs_[0] + rs_[1] + rs_[2] + rs_[3];
  ss = rss_[0] + rss_[1] + rss_[2] + rss_[3];
  float mu = s * (1.f / 1024.f);
  float var = ss * (1.f / 1024.f) - mu * mu;
  float rstd = rsqrtf(var + 1e-5f);
  float4 gv = *(const float4*)(g + threadIdx.x * 4);
  float4 bv = *(const float4*)(b + threadIdx.x * 4);
  uint32_t lo = (uint32_t)f2bf((v.x - mu) * rstd * gv.x + bv.x) |
                ((uint32_t)f2bf((v.y - mu) * rstd * gv.y + bv.y) << 16);
  uint32_t hi = (uint32_t)f2bf((v.z - mu) * rstd * gv.z + bv.z) |
                ((uint32_t)f2bf((v.w - mu) * rstd * gv.w + bv.w) << 16);
  uint2 o; o.x = lo; o.y = hi;
  *(uint2*)(out + (size_t)row * 1024 + threadIdx.x * 4) = o;
}

// ---------------- deep-pipelined GEMM: C = A(bf16 MxK) * BT(bf16 NxK) ----------------
// BM=256 BN=128 BK=64, 8 waves (4Mx2N), ring-3 LDS (144KB), prefetch 2 K-tiles ahead,
// counted vmcnt (6 steady), 2 phases/K-tile of 16 MFMA, T2 row-XOR swizzle, T5 setprio.
#define STAGEA(slot, tnext, is)                                               \
  __builtin_amdgcn_global_load_lds(                                           \
      (gu32*)((const char*)(A + (size_t)(bm * 256 + (is) * 64 + srow) * K +   \
                            (size_t)(tnext) * 64) + ssw),                     \
      (lu32*)&lds[(slot) * 24576 + (is) * 4096 + wid * 512], 16, 0, 0)
#define STAGEB(slot, tnext, is)                                               \
  __builtin_amdgcn_global_load_lds(                                           \
      (gu32*)((const char*)(BT + (size_t)(bn * 128 + (is) * 64 + srow) * K +  \
                            (size_t)(tnext) * 64) + ssw),                     \
      (lu32*)&lds[(slot) * 24576 + 16384 + (is) * 4096 + wid * 512], 16, 0, 0)

template <int MODE>
__global__ __launch_bounds__(512, 2) void gemm8p(
    const u16* __restrict__ A, const u16* __restrict__ BT,
    int M, int N, int K,
    const float* __restrict__ bias, const float* __restrict__ resid,
    float* __restrict__ outf,
    u16* __restrict__ ob0, u16* __restrict__ ob1, u16* __restrict__ ob2) {
  __shared__ __align__(16) u16 lds[73728];  // 3 x (A 256x64 + B 128x64) = 144 KB
  const int tid = threadIdx.x, lane = tid & 63, wid = tid >> 6;
  const int wr = wid >> 1, wc = wid & 1;
  const int bm = blockIdx.y, bn = blockIdx.x;
  const int l15 = lane & 15, lhi = lane >> 4;
  const int srow = tid >> 3;
  const int ssw = ((tid & 7) * 16) ^ ((srow & 7) << 4);
  const int cs0 = (lhi * 8) ^ ((l15 & 7) << 3);
  const int cs1 = (32 + lhi * 8) ^ ((l15 & 7) << 3);
  const int arow = (wr * 64 + l15) * 64;
  const int brow = (wc * 64 + l15) * 64;

  f32x4 acc[4][4];
#pragma unroll
  for (int i = 0; i < 4; ++i)
#pragma unroll
    for (int j = 0; j < 4; ++j) acc[i][j] = (f32x4){0.f, 0.f, 0.f, 0.f};

  const int NT = K >> 6;

#pragma unroll
  for (int t0 = 0; t0 < 3; ++t0) {
    STAGEA(t0, t0, 0); STAGEA(t0, t0, 1); STAGEA(t0, t0, 2); STAGEA(t0, t0, 3);
    STAGEB(t0, t0, 0); STAGEB(t0, t0, 1);
  }
  asm volatile("s_waitcnt vmcnt(12)" ::: "memory");
  __builtin_amdgcn_s_barrier();

  int s = 0, sn = 2;
  for (int t = 0; t < NT; ++t) {
    const bool hasPre = (t + 2) < NT;
    const int aoff = s * 24576, boff = s * 24576 + 16384;

    bf16x8 bfr[4][2], afr[2][2];
#pragma unroll
    for (int ni = 0; ni < 4; ++ni) {
      bfr[ni][0] = *(const bf16x8*)&lds[boff + brow + ni * 1024 + cs0];
      bfr[ni][1] = *(const bf16x8*)&lds[boff + brow + ni * 1024 + cs1];
    }
    afr[0][0] = *(const bf16x8*)&lds[aoff + arow + cs0];
    afr[0][1] = *(const bf16x8*)&lds[aoff + arow + cs1];
    afr[1][0] = *(const bf16x8*)&lds[aoff + arow + 1024 + cs0];
    afr[1][1] = *(const bf16x8*)&lds[aoff + arow + 1024 + cs1];
    if (hasPre) { STAGEA(sn, t + 2, 0); STAGEA(sn, t + 2, 1); STAGEB(sn, t + 2, 0); }
    __builtin_amdgcn_s_barrier();
    __builtin_amdgcn_s_setprio(1);
#pragma unroll
    for (int ml = 0; ml < 2; ++ml)
#pragma unroll
      for (int ni = 0; ni < 4; ++ni) {
        acc[ml][ni] = __builtin_amdgcn_mfma_f32_16x16x32_bf16(afr[ml][0], bfr[ni][0], acc[ml][ni], 0, 0, 0);
        acc[ml][ni] = __builtin_amdgcn_mfma_f32_16x16x32_bf16(afr[ml][1], bfr[ni][1], acc[ml][ni], 0, 0, 0);
      }
    __builtin_amdgcn_s_setprio(0);
    __builtin_amdgcn_s_barrier();

    afr[0][0] = *(const bf16x8*)&lds[aoff + arow + 2048 + cs0];
    afr[0][1] = *(const bf16x8*)&lds[aoff + arow + 2048 + cs1];
    afr[1][0] = *(const bf16x8*)&lds[aoff + arow + 3072 + cs0];
    afr[1][1] = *(const bf16x8*)&lds[aoff + arow + 3072 + cs1];
    if (hasPre) { STAGEA(sn, t + 2, 2); STAGEA(sn, t + 2, 3); STAGEB(sn, t + 2, 1); }
    __builtin_amdgcn_s_barrier();
    __builtin_amdgcn_s_setprio(1);
#pragma unroll
    for (int ml = 0; ml < 2; ++ml)
#pragma unroll
      for (int ni = 0; ni < 4; ++ni) {
        acc[2 + ml][ni] = __builtin_amdgcn_mfma_f32_16x16x32_bf16(afr[ml][0], bfr[ni][0], acc[2 + ml][ni], 0, 0, 0);
        acc[2 + ml][ni] = __builtin_amdgcn_mfma_f32_16x16x32_bf16(afr[ml][1], bfr[ni][1], acc[2 + ml][ni], 0, 0, 0);
      }
    __builtin_amdgcn_s_setprio(0);
    if (hasPre) {
      asm volatile("s_waitcnt vmcnt(6)" ::: "memory");
    } else if (t + 1 < NT) {
      asm volatile("s_waitcnt vmcnt(0)" ::: "memory");
    }
    __builtin_amdgcn_s_barrier();

    s = (s == 2) ? 0 : s + 1;
    sn = (sn == 2) ? 0 : sn + 1;
  }

#pragma unroll
  for (int mi = 0; mi < 4; ++mi) {
#pragma unroll
    for (int ni = 0; ni < 4; ++ni) {
      int col = bn * 128 + wc * 64 + ni * 16 + l15;
      int rbase = bm * 256 + wr * 64 + mi * 16 + lhi * 4;
#pragma unroll
      for (int r = 0; r < 4; ++r) {
        float v = acc[mi][ni][r];
        int rg = rbase + r;
        if (MODE == 0) {
          int b = rg >> 11, tt = rg & 2047;
          int cm = col & 1023, h = cm >> 6, d = cm & 63;
          size_t bh = (size_t)(b * 16 + h);
          if (col < 1024)
            ob0[(bh * 2048 + tt) * 64 + d] = f2bf(v * QSCALE);
          else if (col < 2048)
            ob1[(bh * 2048 + tt) * 64 + d] = f2bf(v);
          else
            ob2[(bh * 64 + d) * 2048 + tt] = f2bf(v);
        } else if (MODE == 1) {
          outf[(size_t)rg * N + col] = v + bias[col] + resid[(size_t)rg * N + col];
        } else if (MODE == 2) {
          ob0[(size_t)rg * N + col] = f2bf(fmaxf(v + bias[col], 0.f));
        } else {
          outf[(size_t)rg * N + col] = fmaxf(v + bias[col], 0.f) + resid[(size_t)rg * N + col];
        }
      }
    }
  }
}

// ---------------- causal flash attention ----------------
// Balanced pairs (block p -> q-tiles 7-p, p), 8 waves x 32 q-rows, swapped QK^T
// (exp2 domain, Q pre-scaled by 0.125*log2e), global_load_lds K/V staging with
// XOR swizzle + ring-3 slots + counted vmcnt, defer-max (THR=8).
__global__ __launch_bounds__(512) void attn_kernel(
    const u16* __restrict__ Qb, const u16* __restrict__ Kb,
    const u16* __restrict__ VTb, u16* __restrict__ O) {
  const int p = blockIdx.x;  // 0..3
  const int bh = blockIdx.y;
  const u16* Q = Qb + (size_t)bh * 2048 * 64;
  const u16* Kp = Kb + (size_t)bh * 2048 * 64;
  const u16* VT = VTb + (size_t)bh * 64 * 2048;
  const int tid = threadIdx.x, lane = tid & 63, wv = tid >> 6;
  const int l15 = lane & 15, lhi = lane >> 4;
  const int srow = tid >> 3;                              // staging row 0..63
  const int sswb = ((tid & 7) * 16) ^ ((srow & 7) << 4);  // inverse-swizzled src byte
  const int rswz = (l15 & 7) << 4;
  const int cb0 = (lhi * 16) ^ rswz;                      // swizzled byte col, ks=0
  const int cb1 = (64 + lhi * 16) ^ rswz;                 // ks=1
  const int b = bh >> 4, h = bh & 15;

  __shared__ __align__(16) u16 KV[3][2][4096];  // [slot][K,V][64x64], 48 KB
  __shared__ u16 Ps[8][32 * 72];

#define STAGEKV(slot, kt)                                                     \
  do {                                                                        \
    __builtin_amdgcn_global_load_lds(                                         \
        (gu32*)((const char*)(Kp + (size_t)((kt)*64 + srow) * 64) + sswb),    \
        (lu32*)&KV[slot][0][wv * 512], 16, 0, 0);                             \
    __builtin_amdgcn_global_load_lds(                                         \
        (gu32*)((const char*)(VT + (size_t)srow * 2048 + (kt)*64) + sswb),    \
        (lu32*)&KV[slot][1][wv * 512], 16, 0, 0);                             \
  } while (0)

#pragma unroll
  for (int pass = 0; pass < 2; ++pass) {
    const int qtile = (pass == 0) ? (7 - p) : p;
    const int qbase = qtile * 256 + wv * 32;
    const int nkt = qtile * 4 + 4;

    bf16x8 qf[2][2];
#pragma unroll
    for (int rf = 0; rf < 2; ++rf)
#pragma unroll
      for (int ks = 0; ks < 2; ++ks)
        qf[rf][ks] = *(const bf16x8*)&Q[(size_t)(qbase + rf * 16 + l15) * 64 + ks * 32 + lhi * 8];

    f32x4 o[2][4];
#pragma unroll
    for (int rf = 0; rf < 2; ++rf)
#pragma unroll
      for (int f = 0; f < 4; ++f) o[rf][f] = (f32x4){0.f, 0.f, 0.f, 0.f};
    float m[2] = {-1e30f, -1e30f};
    float l[2] = {0.f, 0.f};

    __syncthreads();  // prior pass's LDS reads complete
    STAGEKV(0, 0);

    int cs = 0;
    for (int kt = 0; kt < nkt; ++kt) {
      if (kt + 1 < nkt) {
        const int ns = (cs == 2) ? 0 : cs + 1;
        STAGEKV(ns, kt + 1);
        asm volatile("s_waitcnt vmcnt(2)" ::: "memory");  // tile kt landed, kt+1 flying
      } else {
        asm volatile("s_waitcnt vmcnt(0)" ::: "memory");
      }
      __syncthreads();

      if (kt * 64 <= qbase + 31) {  // wave has unmasked rows in this tile
        const char* Kbase = (const char*)&KV[cs][0][0];
        const char* Vbase = (const char*)&KV[cs][1][0];

        f32x4 s[2][4];
#pragma unroll
        for (int rf = 0; rf < 2; ++rf)
#pragma unroll
          for (int jt = 0; jt < 4; ++jt) s[rf][jt] = (f32x4){0.f, 0.f, 0.f, 0.f};
#pragma unroll
        for (int ks = 0; ks < 2; ++ks) {
          const int cbyte = ks ? cb1 : cb0;
#pragma unroll
          for (int jt = 0; jt < 4; ++jt) {
            bf16x8 kf = *(const bf16x8*)(Kbase + (jt * 16 + l15) * 128 + cbyte);
            s[0][jt] = __builtin_amdgcn_mfma_f32_16x16x32_bf16(kf, qf[0][ks], s[0][jt], 0, 0, 0);
            s[1][jt] = __builtin_amdgcn_mfma_f32_16x16x32_bf16(kf, qf[1][ks], s[1][jt], 0, 0, 0);
          }
        }

        if (kt * 64 + 63 > qbase) {  // diagonal-crossing: causal mask
#pragma unroll
          for (int rf = 0; rf < 2; ++rf) {
            int qg = qbase + rf * 16 + l15;
#pragma unroll
            for (int jt = 0; jt < 4; ++jt)
#pragma unroll
              for (int r = 0; r < 4; ++r) {
                int kg = kt * 64 + jt * 16 + lhi * 4 + r;
                if (kg > qg) s[rf][jt][r] = -1e30f;
              }
          }
        }

        // ---- row max (lane-local + 2 shfl), defer-max rescale ----
        float mr[2];
#pragma unroll
        for (int rf = 0; rf < 2; ++rf) {
          float v = fmaxf(fmaxf(s[rf][0][0], s[rf][0][1]), fmaxf(s[rf][0][2], s[rf][0][3]));
#pragma unroll
          for (int jt = 1; jt < 4; ++jt)
            v = fmaxf(v, fmaxf(fmaxf(s[rf][jt][0], s[rf][jt][1]),
                               fmaxf(s[rf][jt][2], s[rf][jt][3])));
          v = fmaxf(v, __shfl_xor(v, 16));
          v = fmaxf(v, __shfl_xor(v, 32));
          mr[rf] = v;
        }
        if (__any((mr[0] > m[0] + 8.f) || (mr[1] > m[1] + 8.f))) {
#pragma unroll
          for (int rf = 0; rf < 2; ++rf) {
            float mn = fmaxf(m[rf], mr[rf]);
            float sc = exp2f(m[rf] - mn);
            l[rf] *= sc;
            m[rf] = mn;
#pragma unroll
            for (int r = 0; r < 4; ++r) {
              float so = __shfl(sc, lhi * 4 + r);
#pragma unroll
              for (int f = 0; f < 4; ++f) o[rf][f][r] *= so;
            }
          }
        }

        // ---- exp2 + row sum ----
#pragma unroll
        for (int rf = 0; rf < 2; ++rf) {
          float rs = 0.f;
#pragma unroll
          for (int jt = 0; jt < 4; ++jt)
#pragma unroll
            for (int r = 0; r < 4; ++r) {
              float pv = exp2f(s[rf][jt][r] - m[rf]);
              s[rf][jt][r] = pv;
              rs += pv;
            }
          rs += __shfl_xor(rs, 16);
          rs += __shfl_xor(rs, 32);
          l[rf] += rs;
        }

        // ---- P -> LDS (wave-private), then PV ----
#pragma unroll
        for (int rf = 0; rf < 2; ++rf)
#pragma unroll
          for (int jt = 0; jt < 4; ++jt) {
            u16x4 pk;
#pragma unroll
            for (int r = 0; r < 4; ++r) pk[r] = f2bf(s[rf][jt][r]);
            *(u16x4*)&Ps[wv][(rf * 16 + l15) * 72 + jt * 16 + lhi * 4] = pk;
          }
#pragma unroll
        for (int ks = 0; ks < 2; ++ks) {
          const int cbyte = ks ? cb1 : cb0;
          bf16x8 pf0 = *(const bf16x8*)&Ps[wv][(l15)*72 + ks * 32 + lhi * 8];
          bf16x8 pf1 = *(const bf16x8*)&Ps[wv][(16 + l15) * 72 + ks * 32 + lhi * 8];
#pragma unroll
          for (int f = 0; f < 4; ++f) {
            bf16x8 vfr = *(const bf16x8*)(Vbase + (f * 16 + l15) * 128 + cbyte);
            o[0][f] = __builtin_amdgcn_mfma_f32_16x16x32_bf16(pf0, vfr, o[0][f], 0, 0, 0);
            o[1][f] = __builtin_amdgcn_mfma_f32_16x16x32_bf16(pf1, vfr, o[1][f], 0, 0, 0);
          }
        }
      }

      cs = (cs == 2) ? 0 : cs + 1;
    }

    // ---- epilogue ----
#pragma unroll
    for (int rf = 0; rf < 2; ++rf)
#pragma unroll
      for (int r = 0; r < 4; ++r) {
        float ld = __shfl(l[rf], lhi * 4 + r);
        float inv = 1.f / ld;
        int t = qbase + rf * 16 + lhi * 4 + r;
#pragma unroll
        for (int f = 0; f < 4; ++f)
          O[((size_t)(b * 2048 + t)) * 1024 + h * 64 + f * 16 + l15] = f2bf(o[rf][f][r] * inv);
      }
  }
#undef STAGEKV
}

extern "C" void kernel_launch(void* const* d_in, const int* in_sizes, int n_in,
                              void* d_out, int out_size, void* d_ws, size_t ws_size,
                              hipStream_t stream) {
  const float* x   = (const float*)d_in[0];
  const float* Wq  = (const float*)d_in[1];
  const float* Wk  = (const float*)d_in[2];
  const float* Wv  = (const float*)d_in[3];
  const float* Wo  = (const float*)d_in[4];
  const float* bo  = (const float*)d_in[5];
  const float* W1  = (const float*)d_in[6];
  const float* b1  = (const float*)d_in[7];
  const float* W2  = (const float*)d_in[8];
  const float* b2  = (const float*)d_in[9];
  const float* g1  = (const float*)d_in[10];
  const float* be1 = (const float*)d_in[11];
  const float* g2  = (const float*)d_in[12];
  const float* be2 = (const float*)d_in[13];

  char* p = (char*)d_ws;
  auto alloc = [&](size_t bytes) {
    char* r = p;
    p += (bytes + 255) & ~(size_t)255;
    return r;
  };
  u16* WqkvT = (u16*)alloc(3072ull * 1024 * 2);
  u16* WoT   = (u16*)alloc(1024ull * 1024 * 2);
  u16* W1T   = (u16*)alloc(4096ull * 1024 * 2);
  u16* W2T   = (u16*)alloc(1024ull * 4096 * 2);
  u16* hln   = (u16*)alloc(8192ull * 1024 * 2);
  u16* Qbuf  = (u16*)alloc(8192ull * 1024 * 2);
  u16* Kbuf  = (u16*)alloc(8192ull * 1024 * 2);
  u16* VTbuf = (u16*)alloc(8192ull * 1024 * 2);
  float* x2  = (float*)alloc(8192ull * 1024 * 4);
  u16* ff1   = (u16*)alloc(8192ull * 4096 * 2);
  u16* Oattn = hln;   // hln dead after QKV GEMM
  u16* h2    = Qbuf;  // Qbuf dead after attention
  if ((size_t)(p - (char*)d_ws) > ws_size) return;

  dim3 tb(32, 8);
  transpose_w<<<dim3(32, 32), tb, 0, stream>>>(Wq, WqkvT, 1024, 1024);
  transpose_w<<<dim3(32, 32), tb, 0, stream>>>(Wk, WqkvT + 1024 * 1024, 1024, 1024);
  transpose_w<<<dim3(32, 32), tb, 0, stream>>>(Wv, WqkvT + 2048 * 1024, 1024, 1024);
  transpose_w<<<dim3(32, 32), tb, 0, stream>>>(Wo, WoT, 1024, 1024);
  transpose_w<<<dim3(128, 32), tb, 0, stream>>>(W1, W1T, 1024, 4096);
  transpose_w<<<dim3(32, 128), tb, 0, stream>>>(W2, W2T, 4096, 1024);

  ln_kernel<<<8192, 256, 0, stream>>>(x, g1, be1, hln);

  gemm8p<0><<<dim3(24, 32), 512, 0, stream>>>(hln, WqkvT, 8192, 3072, 1024,
                                              nullptr, nullptr, nullptr,
                                              Qbuf, Kbuf, VTbuf);

  attn_kernel<<<dim3(4, 64), 512, 0, stream>>>(Qbuf, Kbuf, VTbuf, Oattn);

  gemm8p<1><<<dim3(8, 32), 512, 0, stream>>>(Oattn, WoT, 8192, 1024, 1024,
                                             bo, x, x2, nullptr, nullptr, nullptr);

  ln_kernel<<<8192, 256, 0, stream>>>(x2, g2, be2, h2);

  gemm8p<2><<<dim3(32, 32), 512, 0, stream>>>(h2, W1T, 8192, 4096, 1024,
                                              b1, nullptr, nullptr, ff1, nullptr, nullptr);

  gemm8p<3><<<dim3(8, 32), 512, 0, stream>>>(ff1, W2T, 8192, 1024, 4096,
                                             b2, x2, (float*)d_out, nullptr, nullptr, nullptr);
}